// Round 1
// baseline (614.525 us; speedup 1.0000x reference)
//
#include <hip/hip_runtime.h>

// Problem constants (from reference): FULL=128, BLOCK=16, C=28, T=8,
// N_OCC=154, SL=(8,72) -> sx=64, t_start=0, nt=5.
#define S0 8

// Kernel 1: build 125-entry LUT mapping window tile position -> packed tile
// index (or -1 if unoccupied). Handles occupancy stored as 1-byte bool OR
// 4-byte int/float: N_OCC=154 > 128, so if the first 512 *bytes* contain
// >128 nonzero bytes the layout must be 1-byte; a 4-byte layout covers only
// 128 elements in those bytes (<=128 nonzero bytes possible).
__global__ void build_lut_kernel(const void* __restrict__ occ_raw,
                                 int* __restrict__ lut) {
    __shared__ int flag[512];
    __shared__ int psum[512];
    __shared__ int cnt8;
    const int t = threadIdx.x;  // 512 threads
    const unsigned char* p8 = (const unsigned char*)occ_raw;
    if (t == 0) cnt8 = 0;
    __syncthreads();
    const unsigned char b = p8[t];
    unsigned long long m = __ballot(b != 0);
    if ((t & 63) == 0) atomicAdd(&cnt8, __popcll(m));
    __syncthreads();
    int o;
    if (cnt8 > 128) {
        o = (b != 0) ? 1 : 0;                                   // 1-byte bool
    } else {
        o = (((const unsigned int*)occ_raw)[t] != 0u) ? 1 : 0;  // 4-byte word
    }
    flag[t] = o;
    psum[t] = o;
    __syncthreads();
    // Hillis-Steele inclusive scan over 512 elements.
    for (int off = 1; off < 512; off <<= 1) {
        int v = (t >= off) ? psum[t - off] : 0;
        __syncthreads();
        psum[t] += v;
        __syncthreads();
    }
    // tile_idx = inclusive_cumsum - 1 at occupied positions.
    if (t < 125) {
        int gx = t / 25;
        int r  = t - gx * 25;
        int gy = r / 5;
        int gz = r - gy * 5;
        int lin = (gx * 8 + gy) * 8 + gz;   // t_start = 0
        lut[t] = flag[lin] ? (psum[lin] - 1) : -1;
    }
}

// Kernel 2: one thread per float4 of output (out laid out (7,1,28,64,64,64)).
// Window offset S0=8 is 0 mod 4 and BLOCK=16, so each aligned z-quad lies in
// a single tile -> one aligned float4 load, one aligned float4 store.
__global__ __launch_bounds__(256) void gather_kernel(
    const float* __restrict__ tiles, const int* __restrict__ lut,
    float* __restrict__ out, int n4) {
    __shared__ int slut[125];
    if (threadIdx.x < 125) slut[threadIdx.x] = lut[threadIdx.x];
    __syncthreads();
    int i = blockIdx.x * 256 + threadIdx.x;
    if (i >= n4) return;
    // Decompose: i = ((((j*28 + c)*64 + x)*64 + y)*16 + z/4)
    int zq = i & 15;           // z / 4
    int t1 = i >> 4;
    int y  = t1 & 63;
    int t2 = t1 >> 6;
    int x  = t2 & 63;
    int t3 = t2 >> 6;          // j*28 + c, in [0,196)
    int j  = t3 / 28;
    int c  = t3 - j * 28;
    int Z = zq * 4 + S0;
    int Y = y + S0;
    int X = x + S0;
    int gz = Z >> 4, bz = Z & 15;
    int gy = Y >> 4, by = Y & 15;
    int gx = X >> 4, bx = X & 15;
    int tidx = slut[(gx * 5 + gy) * 5 + gz];
    float4 v = make_float4(0.f, 0.f, 0.f, 0.f);
    if (tidx >= 0) {
        size_t src = (((size_t)tidx * 7 + (size_t)j) * 28 + (size_t)c) * 4096
                   + (size_t)(bx * 256 + by * 16 + bz);
        v = *(const float4*)(tiles + src);
    }
    *(float4*)(out + (size_t)i * 4) = v;
}

extern "C" void kernel_launch(void* const* d_in, const int* in_sizes, int n_in,
                              void* d_out, int out_size, void* d_ws, size_t ws_size,
                              hipStream_t stream) {
    const float* tiles = (const float*)d_in[0];   // (154,7,28,16,16,16) f32
    const void*  occ   = d_in[1];                 // (8,8,8) bool (layout auto-detected)
    float* out = (float*)d_out;                   // (7,1,28,64,64,64) f32
    int* lut = (int*)d_ws;                        // 125 ints of scratch

    build_lut_kernel<<<1, 512, 0, stream>>>(occ, lut);

    int n4 = out_size / 4;                        // 12,845,056 float4 groups
    int blocks = (n4 + 255) / 256;                // 50,176 blocks
    gather_kernel<<<blocks, 256, 0, stream>>>(tiles, lut, out, n4);
}

// Round 2
// 607.465 us; speedup vs baseline: 1.0116x; 1.0116x over previous
//
#include <hip/hip_runtime.h>

// Problem constants (from reference): FULL=128, BLOCK=16, C=28, T=8,
// N_OCC=154, SL=(8,72) -> sx=64, t_start=0, nt=5.
#define S0 8

typedef float f4 __attribute__((ext_vector_type(4)));

// Kernel 1: build 125-entry LUT mapping window tile position -> packed tile
// index (or -1 if unoccupied). Handles occupancy stored as 1-byte bool OR
// 4-byte int/float: N_OCC=154 > 128, so if the first 512 *bytes* contain
// >128 nonzero bytes the layout must be 1-byte; a 4-byte layout covers only
// 128 elements in those bytes (<=128 nonzero bytes possible).
__global__ void build_lut_kernel(const void* __restrict__ occ_raw,
                                 int* __restrict__ lut) {
    __shared__ int flag[512];
    __shared__ int psum[512];
    __shared__ int cnt8;
    const int t = threadIdx.x;  // 512 threads
    const unsigned char* p8 = (const unsigned char*)occ_raw;
    if (t == 0) cnt8 = 0;
    __syncthreads();
    const unsigned char b = p8[t];
    unsigned long long m = __ballot(b != 0);
    if ((t & 63) == 0) atomicAdd(&cnt8, __popcll(m));
    __syncthreads();
    int o;
    if (cnt8 > 128) {
        o = (b != 0) ? 1 : 0;                                   // 1-byte bool
    } else {
        o = (((const unsigned int*)occ_raw)[t] != 0u) ? 1 : 0;  // 4-byte word
    }
    flag[t] = o;
    psum[t] = o;
    __syncthreads();
    // Hillis-Steele inclusive scan over 512 elements.
    for (int off = 1; off < 512; off <<= 1) {
        int v = (t >= off) ? psum[t - off] : 0;
        __syncthreads();
        psum[t] += v;
        __syncthreads();
    }
    // tile_idx = inclusive_cumsum - 1 at occupied positions.
    if (t < 125) {
        int gx = t / 25;
        int r  = t - gx * 25;
        int gy = r / 5;
        int gz = r - gy * 5;
        int lin = (gx * 8 + gy) * 8 + gz;   // t_start = 0
        lut[t] = flag[lin] ? (psum[lin] - 1) : -1;
    }
}

// Kernel 2: two float4s per thread (at i and i+half), out laid out
// (7,1,28,64,64,64). Window offset S0=8 is 0 mod 4 and BLOCK=16, so each
// aligned z-quad lies in a single tile -> one aligned 16B load + 16B store.
// Nontemporal on both sides: streaming data, no reuse -> keep L2 clean.
// n4 = 12,845,056 = 2 * half; half = 6,422,528 = 25,088 * 256 (exact, no
// bounds check needed).
__global__ __launch_bounds__(256) void gather_kernel(
    const float* __restrict__ tiles, const int* __restrict__ lut,
    float* __restrict__ out, int half) {
    __shared__ int slut[125];
    if (threadIdx.x < 125) slut[threadIdx.x] = lut[threadIdx.x];
    __syncthreads();
    const int i0 = blockIdx.x * 256 + threadIdx.x;
#pragma unroll
    for (int u = 0; u < 2; ++u) {
        const int i = i0 + u * half;
        // Decompose: i = ((((j*28 + c)*64 + x)*64 + y)*16 + z/4)
        int zq = i & 15;           // z / 4
        int t1 = i >> 4;
        int y  = t1 & 63;
        int t2 = t1 >> 6;
        int x  = t2 & 63;
        int t3 = t2 >> 6;          // j*28 + c, in [0,196)
        int j  = t3 / 28;
        int c  = t3 - j * 28;
        int Z = zq * 4 + S0;
        int Y = y + S0;
        int X = x + S0;
        int gz = Z >> 4, bz = Z & 15;
        int gy = Y >> 4, by = Y & 15;
        int gx = X >> 4, bx = X & 15;
        int tidx = slut[(gx * 5 + gy) * 5 + gz];
        f4 v = (f4)(0.0f);
        if (tidx >= 0) {
            size_t src = (((size_t)tidx * 7 + (size_t)j) * 28 + (size_t)c) * 4096
                       + (size_t)(bx * 256 + by * 16 + bz);
            v = __builtin_nontemporal_load((const f4*)(tiles + src));
        }
        __builtin_nontemporal_store(v, (f4*)(out + (size_t)i * 4));
    }
}

extern "C" void kernel_launch(void* const* d_in, const int* in_sizes, int n_in,
                              void* d_out, int out_size, void* d_ws, size_t ws_size,
                              hipStream_t stream) {
    const float* tiles = (const float*)d_in[0];   // (154,7,28,16,16,16) f32
    const void*  occ   = d_in[1];                 // (8,8,8) bool (layout auto-detected)
    float* out = (float*)d_out;                   // (7,1,28,64,64,64) f32
    int* lut = (int*)d_ws;                        // 125 ints of scratch

    build_lut_kernel<<<1, 512, 0, stream>>>(occ, lut);

    int half = out_size / 8;                      // 6,422,528 float4 pairs
    int blocks = half / 256;                      // 25,088 blocks, exact
    gather_kernel<<<blocks, 256, 0, stream>>>(tiles, lut, out, half);
}